// Round 8
// baseline (162.779 us; speedup 1.0000x reference)
//
#include <hip/hip_runtime.h>

#define B_DIM 8
#define E_DIM 16
#define G_DIM 20000
#define P_DIM 512
#define P4    128             // float4 columns per P row
#define NCHUNK 80             // g-interleave stride; 20000 = 80*250 exactly
#define NITER  250            // rows per block (50 groups of 5)
// d_ws layout
#define WS_XT_OFF   0                 // 640 KB  xT  f32 [G][B]
#define WS_BM_OFF   (1u << 20)        // 1.28 MB packed mask bits
#define WS_PART_OFF (4u << 20)        // 21 MB   partials f32 [E*NCHUNK][B][P]

typedef float floatx4 __attribute__((ext_vector_type(4)));   // builtin-compatible

// Fused prepass: pack mask bits; threads with i<G also transpose x.
// bit j of bm[i>>6] <=> mask[(i&~63)+j] != 0   (grid = G*P/256 = 40000 exactly)
__global__ __launch_bounds__(256) void prep_kernel(const float* __restrict__ x,
                                                   const float* __restrict__ mask,
                                                   float* __restrict__ xT,
                                                   unsigned long long* __restrict__ bm) {
    int i = blockIdx.x * 256 + threadIdx.x;
    unsigned long long bal = __ballot(mask[i] != 0.0f);
    if ((threadIdx.x & 63) == 0) bm[i >> 6] = bal;
    if (i < G_DIM) {
#pragma unroll
        for (int b = 0; b < B_DIM; ++b)
            xT[i * B_DIM + b] = x[b * G_DIM + i];
    }
}

// one g-row: select 4 weight lanes by mask nibble, 8 batch FMAs
#define STEP(wv, t, xo) { \
    float wmx = ((t) & 1u) ? wv.x : 0.0f; \
    float wmy = ((t) & 2u) ? wv.y : 0.0f; \
    float wmz = ((t) & 4u) ? wv.z : 0.0f; \
    float wmw = ((t) & 8u) ? wv.w : 0.0f; \
    float xv; \
    xv = xr[(xo) + 0]; a0.x = fmaf(xv, wmx, a0.x); a0.y = fmaf(xv, wmy, a0.y); a0.z = fmaf(xv, wmz, a0.z); a0.w = fmaf(xv, wmw, a0.w); \
    xv = xr[(xo) + 1]; a1.x = fmaf(xv, wmx, a1.x); a1.y = fmaf(xv, wmy, a1.y); a1.z = fmaf(xv, wmz, a1.z); a1.w = fmaf(xv, wmw, a1.w); \
    xv = xr[(xo) + 2]; a2.x = fmaf(xv, wmx, a2.x); a2.y = fmaf(xv, wmy, a2.y); a2.z = fmaf(xv, wmz, a2.z); a2.w = fmaf(xv, wmw, a2.w); \
    xv = xr[(xo) + 3]; a3.x = fmaf(xv, wmx, a3.x); a3.y = fmaf(xv, wmy, a3.y); a3.z = fmaf(xv, wmz, a3.z); a3.w = fmaf(xv, wmw, a3.w); \
    xv = xr[(xo) + 4]; a4.x = fmaf(xv, wmx, a4.x); a4.y = fmaf(xv, wmy, a4.y); a4.z = fmaf(xv, wmz, a4.z); a4.w = fmaf(xv, wmw, a4.w); \
    xv = xr[(xo) + 5]; a5.x = fmaf(xv, wmx, a5.x); a5.y = fmaf(xv, wmy, a5.y); a5.z = fmaf(xv, wmz, a5.z); a5.w = fmaf(xv, wmw, a5.w); \
    xv = xr[(xo) + 6]; a6.x = fmaf(xv, wmx, a6.x); a6.y = fmaf(xv, wmy, a6.y); a6.z = fmaf(xv, wmz, a6.z); a6.w = fmaf(xv, wmw, a6.w); \
    xv = xr[(xo) + 7]; a7.x = fmaf(xv, wmx, a7.x); a7.y = fmaf(xv, wmy, a7.y); a7.z = fmaf(xv, wmz, a7.z); a7.w = fmaf(xv, wmw, a7.w); }

__global__ __launch_bounds__(128) void masked_embed_kernel(const float* __restrict__ xT,
                                                           const float* __restrict__ w,
                                                           const unsigned int* __restrict__ bm32,
                                                           float* __restrict__ part) {
    const int p4 = threadIdx.x;        // 0..127
    const int c  = blockIdx.x;         // 0..NCHUNK-1 (interleaved g: rows c + NCHUNK*k)
    const int e  = blockIdx.y;

    const int WSTEP = NCHUNK * P4;     // floatx4 per g-step  (10240)
    const int BSTEP = NCHUNK * 16;     // bm dwords per step  (1280)
    const int XSTEP = NCHUNK * B_DIM;  // xT floats per step  (640)

    const floatx4* __restrict__ wgp =
        reinterpret_cast<const floatx4*>(w) + (size_t)e * G_DIM * P4 + (size_t)c * P4 + p4;
    const unsigned int* __restrict__ bmp = bm32 + (size_t)c * 16 + (p4 >> 3);
    const float* __restrict__ xr = xT + (size_t)c * B_DIM;    // block-uniform
    const unsigned int sh = (p4 & 7) * 4;

    float4 a0 = make_float4(0.f, 0.f, 0.f, 0.f), a1 = a0, a2 = a0, a3 = a0,
           a4 = a0, a5 = a0, a6 = a0, a7 = a0;

#pragma unroll 1
    for (int k = 0; k < NITER / 5; ++k) {    // 50 iterations, 5 g-rows each
        unsigned int t0 = bmp[0 * BSTEP] >> sh;
        unsigned int t1 = bmp[1 * BSTEP] >> sh;
        unsigned int t2 = bmp[2 * BSTEP] >> sh;
        unsigned int t3 = bmp[3 * BSTEP] >> sh;
        unsigned int t4 = bmp[4 * BSTEP] >> sh;
        // exec-masked, nontemporal weight loads: lanes whose mask nibble is 0
        // issue no memory request; whole-sector skips cut HBM fetch.
        floatx4 w0 = (floatx4)0.0f, w1 = w0, w2 = w0, w3 = w0, w4 = w0;
        if (t0 & 15u) w0 = __builtin_nontemporal_load(wgp + 0 * WSTEP);
        if (t1 & 15u) w1 = __builtin_nontemporal_load(wgp + 1 * WSTEP);
        if (t2 & 15u) w2 = __builtin_nontemporal_load(wgp + 2 * WSTEP);
        if (t3 & 15u) w3 = __builtin_nontemporal_load(wgp + 3 * WSTEP);
        if (t4 & 15u) w4 = __builtin_nontemporal_load(wgp + 4 * WSTEP);
        STEP(w0, t0, 0 * XSTEP)
        STEP(w1, t1, 1 * XSTEP)
        STEP(w2, t2, 2 * XSTEP)
        STEP(w3, t3, 3 * XSTEP)
        STEP(w4, t4, 4 * XSTEP)
        wgp += 5 * WSTEP; bmp += 5 * BSTEP; xr += 5 * XSTEP;
    }

    // contiguous partial store: part[(e*NCHUNK + c)][b][p]
    float* pb = part + (size_t)(e * NCHUNK + c) * B_DIM * P_DIM + p4 * 4;
#define PSTORE(acc, b) *reinterpret_cast<float4*>(pb + (size_t)(b) * P_DIM) = acc;
    PSTORE(a0, 0) PSTORE(a1, 1) PSTORE(a2, 2) PSTORE(a3, 3)
    PSTORE(a4, 4) PSTORE(a5, 5) PSTORE(a6, 6) PSTORE(a7, 7)
#undef PSTORE
}

// out[b][e][p] = bias[e][p] + sum_c part[(e*NCHUNK+c)][b][p]
__global__ __launch_bounds__(128) void reduce_kernel(const float* __restrict__ part,
                                                     const float* __restrict__ bias,
                                                     float* __restrict__ out) {
    const int p4 = threadIdx.x;   // 0..127
    const int e  = blockIdx.x;    // 0..15
    const int b  = blockIdx.y;    // 0..7

    const int CSTEP = B_DIM * P4; // float4 stride per c (1024)
    const float4* __restrict__ pp =
        reinterpret_cast<const float4*>(part) + ((size_t)(e * NCHUNK) * B_DIM + b) * P4 + p4;

    float4 s = make_float4(0.f, 0.f, 0.f, 0.f);
#pragma unroll 1
    for (int c = 0; c < NCHUNK; c += 8) {
        float4 q0 = pp[0 * CSTEP];
        float4 q1 = pp[1 * CSTEP];
        float4 q2 = pp[2 * CSTEP];
        float4 q3 = pp[3 * CSTEP];
        float4 q4 = pp[4 * CSTEP];
        float4 q5 = pp[5 * CSTEP];
        float4 q6 = pp[6 * CSTEP];
        float4 q7 = pp[7 * CSTEP];
        s.x += q0.x + q1.x + q2.x + q3.x + q4.x + q5.x + q6.x + q7.x;
        s.y += q0.y + q1.y + q2.y + q3.y + q4.y + q5.y + q6.y + q7.y;
        s.z += q0.z + q1.z + q2.z + q3.z + q4.z + q5.z + q6.z + q7.z;
        s.w += q0.w + q1.w + q2.w + q3.w + q4.w + q5.w + q6.w + q7.w;
        pp += 8 * CSTEP;
    }
    float4 bv = reinterpret_cast<const float4*>(bias)[e * P4 + p4];
    s.x += bv.x; s.y += bv.y; s.z += bv.z; s.w += bv.w;
    reinterpret_cast<float4*>(out)[((size_t)b * E_DIM + e) * P4 + p4] = s;
}

extern "C" void kernel_launch(void* const* d_in, const int* in_sizes, int n_in,
                              void* d_out, int out_size, void* d_ws, size_t ws_size,
                              hipStream_t stream) {
    const float* x    = (const float*)d_in[0];   // [B, G]
    const float* w    = (const float*)d_in[1];   // [E, G, P]
    const float* bias = (const float*)d_in[2];   // [E, P]
    const float* mask = (const float*)d_in[3];   // [G, P]
    float* out = (float*)d_out;                  // [B, E, P] fp32

    float* xT = (float*)((char*)d_ws + WS_XT_OFF);
    unsigned long long* bm = (unsigned long long*)((char*)d_ws + WS_BM_OFF);
    float* part = (float*)((char*)d_ws + WS_PART_OFF);

    prep_kernel<<<dim3((G_DIM * P_DIM) / 256), dim3(256), 0, stream>>>(x, mask, xT, bm);
    masked_embed_kernel<<<dim3(NCHUNK, E_DIM), dim3(128), 0, stream>>>(
        xT, w, (const unsigned int*)bm, part);
    reduce_kernel<<<dim3(E_DIM, B_DIM), dim3(128), 0, stream>>>(part, bias, out);
}

// Round 9
// 144.431 us; speedup vs baseline: 1.1270x; 1.1270x over previous
//
#include <hip/hip_runtime.h>

#define B_DIM 8
#define E_DIM 16
#define G_DIM 20000
#define P_DIM 512
#define P4    128             // float4 columns per P row
// d_ws layout
#define WS_XT_OFF   0                 // 640 KB  xT  f32 [G][B]
#define WS_BM_OFF   (1u << 20)        // 1.28 MB packed mask bits
#define WS_PART_OFF (4u << 20)        // partials f32 [E*NCHUNK][B][P]

typedef float floatx4 __attribute__((ext_vector_type(4)));   // builtin-compatible

// Fused prepass: pack mask bits; threads with i<G also transpose x.
// bit j of bm[i>>6] <=> mask[(i&~63)+j] != 0   (grid = G*P/256 = 40000 exactly)
__global__ __launch_bounds__(256) void prep_kernel(const float* __restrict__ x,
                                                   const float* __restrict__ mask,
                                                   float* __restrict__ xT,
                                                   unsigned long long* __restrict__ bm) {
    int i = blockIdx.x * 256 + threadIdx.x;
    unsigned long long bal = __ballot(mask[i] != 0.0f);
    if ((threadIdx.x & 63) == 0) bm[i >> 6] = bal;
    if (i < G_DIM) {
#pragma unroll
        for (int b = 0; b < B_DIM; ++b)
            xT[i * B_DIM + b] = x[b * G_DIM + i];
    }
}

// one g-row: select 4 weight lanes by mask nibble, 8 batch FMAs
#define STEP(wv, t, xo) { \
    float wmx = ((t) & 1u) ? wv.x : 0.0f; \
    float wmy = ((t) & 2u) ? wv.y : 0.0f; \
    float wmz = ((t) & 4u) ? wv.z : 0.0f; \
    float wmw = ((t) & 8u) ? wv.w : 0.0f; \
    float xv; \
    xv = xr[(xo) + 0]; a0.x = fmaf(xv, wmx, a0.x); a0.y = fmaf(xv, wmy, a0.y); a0.z = fmaf(xv, wmz, a0.z); a0.w = fmaf(xv, wmw, a0.w); \
    xv = xr[(xo) + 1]; a1.x = fmaf(xv, wmx, a1.x); a1.y = fmaf(xv, wmy, a1.y); a1.z = fmaf(xv, wmz, a1.z); a1.w = fmaf(xv, wmw, a1.w); \
    xv = xr[(xo) + 2]; a2.x = fmaf(xv, wmx, a2.x); a2.y = fmaf(xv, wmy, a2.y); a2.z = fmaf(xv, wmz, a2.z); a2.w = fmaf(xv, wmw, a2.w); \
    xv = xr[(xo) + 3]; a3.x = fmaf(xv, wmx, a3.x); a3.y = fmaf(xv, wmy, a3.y); a3.z = fmaf(xv, wmz, a3.z); a3.w = fmaf(xv, wmw, a3.w); \
    xv = xr[(xo) + 4]; a4.x = fmaf(xv, wmx, a4.x); a4.y = fmaf(xv, wmy, a4.y); a4.z = fmaf(xv, wmz, a4.z); a4.w = fmaf(xv, wmw, a4.w); \
    xv = xr[(xo) + 5]; a5.x = fmaf(xv, wmx, a5.x); a5.y = fmaf(xv, wmy, a5.y); a5.z = fmaf(xv, wmz, a5.z); a5.w = fmaf(xv, wmw, a5.w); \
    xv = xr[(xo) + 6]; a6.x = fmaf(xv, wmx, a6.x); a6.y = fmaf(xv, wmy, a6.y); a6.z = fmaf(xv, wmz, a6.z); a6.w = fmaf(xv, wmw, a6.w); \
    xv = xr[(xo) + 7]; a7.x = fmaf(xv, wmx, a7.x); a7.y = fmaf(xv, wmy, a7.y); a7.z = fmaf(xv, wmz, a7.z); a7.w = fmaf(xv, wmw, a7.w); }

template <int NC, int NITER>
__global__ __launch_bounds__(128) void masked_embed_kernel(const float* __restrict__ xT,
                                                           const float* __restrict__ w,
                                                           const unsigned int* __restrict__ bm32,
                                                           float* __restrict__ part) {
    const int p4 = threadIdx.x;        // 0..127
    const int c  = blockIdx.x;         // 0..NC-1 (interleaved g: rows c + NC*k)
    const int e  = blockIdx.y;

    const int WSTEP = NC * P4;         // floatx4 per g-step
    const int BSTEP = NC * 16;         // bm dwords per step
    const int XSTEP = NC * B_DIM;      // xT floats per step

    const floatx4* __restrict__ wgp =
        reinterpret_cast<const floatx4*>(w) + (size_t)e * G_DIM * P4 + (size_t)c * P4 + p4;
    const unsigned int* __restrict__ bmp = bm32 + (size_t)c * 16 + (p4 >> 3);
    const float* __restrict__ xr = xT + (size_t)c * B_DIM;    // block-uniform
    const unsigned int sh = (p4 & 7) * 4;

    float4 a0 = make_float4(0.f, 0.f, 0.f, 0.f), a1 = a0, a2 = a0, a3 = a0,
           a4 = a0, a5 = a0, a6 = a0, a7 = a0;

#pragma unroll 1
    for (int k = 0; k < NITER / 5; ++k) {    // groups of 5 g-rows
        unsigned int t0 = bmp[0 * BSTEP] >> sh;
        unsigned int t1 = bmp[1 * BSTEP] >> sh;
        unsigned int t2 = bmp[2 * BSTEP] >> sh;
        unsigned int t3 = bmp[3 * BSTEP] >> sh;
        unsigned int t4 = bmp[4 * BSTEP] >> sh;
        // exec-masked, nontemporal weight loads: lanes whose mask nibble is 0
        // issue no memory request; whole-sector skips cut HBM fetch.
        floatx4 w0 = (floatx4)0.0f, w1 = w0, w2 = w0, w3 = w0, w4 = w0;
        if (t0 & 15u) w0 = __builtin_nontemporal_load(wgp + 0 * WSTEP);
        if (t1 & 15u) w1 = __builtin_nontemporal_load(wgp + 1 * WSTEP);
        if (t2 & 15u) w2 = __builtin_nontemporal_load(wgp + 2 * WSTEP);
        if (t3 & 15u) w3 = __builtin_nontemporal_load(wgp + 3 * WSTEP);
        if (t4 & 15u) w4 = __builtin_nontemporal_load(wgp + 4 * WSTEP);
        STEP(w0, t0, 0 * XSTEP)
        STEP(w1, t1, 1 * XSTEP)
        STEP(w2, t2, 2 * XSTEP)
        STEP(w3, t3, 3 * XSTEP)
        STEP(w4, t4, 4 * XSTEP)
        wgp += 5 * WSTEP; bmp += 5 * BSTEP; xr += 5 * XSTEP;
    }

    // contiguous partial store: part[(e*NC + c)][b][p]
    float* pb = part + (size_t)(e * NC + c) * B_DIM * P_DIM + p4 * 4;
#define PSTORE(acc, b) *reinterpret_cast<float4*>(pb + (size_t)(b) * P_DIM) = acc;
    PSTORE(a0, 0) PSTORE(a1, 1) PSTORE(a2, 2) PSTORE(a3, 3)
    PSTORE(a4, 4) PSTORE(a5, 5) PSTORE(a6, 6) PSTORE(a7, 7)
#undef PSTORE
}

// out[b][e][p] = bias[e][p] + sum_c part[(e*NC+c)][b][p]
template <int NC>
__global__ __launch_bounds__(128) void reduce_kernel(const float* __restrict__ part,
                                                     const float* __restrict__ bias,
                                                     float* __restrict__ out) {
    const int p4 = threadIdx.x;   // 0..127
    const int e  = blockIdx.x;    // 0..15
    const int b  = blockIdx.y;    // 0..7

    const int CSTEP = B_DIM * P4; // float4 stride per c (1024)
    const float4* __restrict__ pp =
        reinterpret_cast<const float4*>(part) + ((size_t)(e * NC) * B_DIM + b) * P4 + p4;

    float4 s = make_float4(0.f, 0.f, 0.f, 0.f);
#pragma unroll 1
    for (int c = 0; c < NC; c += 8) {
        float4 q0 = pp[0 * CSTEP];
        float4 q1 = pp[1 * CSTEP];
        float4 q2 = pp[2 * CSTEP];
        float4 q3 = pp[3 * CSTEP];
        float4 q4 = pp[4 * CSTEP];
        float4 q5 = pp[5 * CSTEP];
        float4 q6 = pp[6 * CSTEP];
        float4 q7 = pp[7 * CSTEP];
        s.x += q0.x + q1.x + q2.x + q3.x + q4.x + q5.x + q6.x + q7.x;
        s.y += q0.y + q1.y + q2.y + q3.y + q4.y + q5.y + q6.y + q7.y;
        s.z += q0.z + q1.z + q2.z + q3.z + q4.z + q5.z + q6.z + q7.z;
        s.w += q0.w + q1.w + q2.w + q3.w + q4.w + q5.w + q6.w + q7.w;
        pp += 8 * CSTEP;
    }
    float4 bv = reinterpret_cast<const float4*>(bias)[e * P4 + p4];
    s.x += bv.x; s.y += bv.y; s.z += bv.z; s.w += bv.w;
    reinterpret_cast<float4*>(out)[((size_t)b * E_DIM + e) * P4 + p4] = s;
}

extern "C" void kernel_launch(void* const* d_in, const int* in_sizes, int n_in,
                              void* d_out, int out_size, void* d_ws, size_t ws_size,
                              hipStream_t stream) {
    const float* x    = (const float*)d_in[0];   // [B, G]
    const float* w    = (const float*)d_in[1];   // [E, G, P]
    const float* bias = (const float*)d_in[2];   // [E, P]
    const float* mask = (const float*)d_in[3];   // [G, P]
    float* out = (float*)d_out;                  // [B, E, P] fp32

    float* xT = (float*)((char*)d_ws + WS_XT_OFF);
    unsigned long long* bm = (unsigned long long*)((char*)d_ws + WS_BM_OFF);
    float* part = (float*)((char*)d_ws + WS_PART_OFF);

    prep_kernel<<<dim3((G_DIM * P_DIM) / 256), dim3(256), 0, stream>>>(x, mask, xT, bm);

    // NCHUNK=200 (25 waves/CU) needs 4MB + 51.2MB of d_ws; fall back to the
    // proven NCHUNK=160 (20 waves/CU) if scratch is too small. ws_size is
    // fixed across calls -> deterministic choice.
    const size_t need200 = (size_t)WS_PART_OFF + (size_t)200 * E_DIM * B_DIM * P_DIM * 4;
    if (ws_size >= need200) {
        masked_embed_kernel<200, 100><<<dim3(200, E_DIM), dim3(128), 0, stream>>>(
            xT, w, (const unsigned int*)bm, part);
        reduce_kernel<200><<<dim3(E_DIM, B_DIM), dim3(128), 0, stream>>>(part, bias, out);
    } else {
        masked_embed_kernel<160, 125><<<dim3(160, E_DIM), dim3(128), 0, stream>>>(
            xT, w, (const unsigned int*)bm, part);
        reduce_kernel<160><<<dim3(E_DIM, B_DIM), dim3(128), 0, stream>>>(part, bias, out);
    }
}

// Round 10
// 143.336 us; speedup vs baseline: 1.1356x; 1.0076x over previous
//
#include <hip/hip_runtime.h>

#define B_DIM 8
#define E_DIM 16
#define G_DIM 20000
#define P_DIM 512
#define P4    128             // float4 columns per P row
#define NCHUNK 160            // g-interleave stride; 20000 = 160*125 exactly
#define NITER  125            // rows per block (25 groups of 5)
// d_ws layout
#define WS_XT_OFF   0                 // 640 KB  xT  f32 [G][B]
#define WS_BM_OFF   (1u << 20)        // 1.28 MB packed mask bits
#define WS_PART_OFF (4u << 20)        // 40 MB   partials f32 [E*NCHUNK][B][P]

typedef float floatx4 __attribute__((ext_vector_type(4)));   // builtin-compatible

// Fused prepass: pack mask bits; threads with i<G also transpose x.
// bit j of bm[i>>6] <=> mask[(i&~63)+j] != 0   (grid = G*P/256 = 40000 exactly)
__global__ __launch_bounds__(256) void prep_kernel(const float* __restrict__ x,
                                                   const float* __restrict__ mask,
                                                   float* __restrict__ xT,
                                                   unsigned long long* __restrict__ bm) {
    int i = blockIdx.x * 256 + threadIdx.x;
    unsigned long long bal = __ballot(mask[i] != 0.0f);
    if ((threadIdx.x & 63) == 0) bm[i >> 6] = bal;
    if (i < G_DIM) {
#pragma unroll
        for (int b = 0; b < B_DIM; ++b)
            xT[i * B_DIM + b] = x[b * G_DIM + i];
    }
}

// one g-row: select 4 weight lanes by mask nibble, 8 batch FMAs
#define STEP(wv, t, xo) { \
    float wmx = ((t) & 1u) ? wv.x : 0.0f; \
    float wmy = ((t) & 2u) ? wv.y : 0.0f; \
    float wmz = ((t) & 4u) ? wv.z : 0.0f; \
    float wmw = ((t) & 8u) ? wv.w : 0.0f; \
    float xv; \
    xv = xr[(xo) + 0]; a0.x = fmaf(xv, wmx, a0.x); a0.y = fmaf(xv, wmy, a0.y); a0.z = fmaf(xv, wmz, a0.z); a0.w = fmaf(xv, wmw, a0.w); \
    xv = xr[(xo) + 1]; a1.x = fmaf(xv, wmx, a1.x); a1.y = fmaf(xv, wmy, a1.y); a1.z = fmaf(xv, wmz, a1.z); a1.w = fmaf(xv, wmw, a1.w); \
    xv = xr[(xo) + 2]; a2.x = fmaf(xv, wmx, a2.x); a2.y = fmaf(xv, wmy, a2.y); a2.z = fmaf(xv, wmz, a2.z); a2.w = fmaf(xv, wmw, a2.w); \
    xv = xr[(xo) + 3]; a3.x = fmaf(xv, wmx, a3.x); a3.y = fmaf(xv, wmy, a3.y); a3.z = fmaf(xv, wmz, a3.z); a3.w = fmaf(xv, wmw, a3.w); \
    xv = xr[(xo) + 4]; a4.x = fmaf(xv, wmx, a4.x); a4.y = fmaf(xv, wmy, a4.y); a4.z = fmaf(xv, wmz, a4.z); a4.w = fmaf(xv, wmw, a4.w); \
    xv = xr[(xo) + 5]; a5.x = fmaf(xv, wmx, a5.x); a5.y = fmaf(xv, wmy, a5.y); a5.z = fmaf(xv, wmz, a5.z); a5.w = fmaf(xv, wmw, a5.w); \
    xv = xr[(xo) + 6]; a6.x = fmaf(xv, wmx, a6.x); a6.y = fmaf(xv, wmy, a6.y); a6.z = fmaf(xv, wmz, a6.z); a6.w = fmaf(xv, wmw, a6.w); \
    xv = xr[(xo) + 7]; a7.x = fmaf(xv, wmx, a7.x); a7.y = fmaf(xv, wmy, a7.y); a7.z = fmaf(xv, wmz, a7.z); a7.w = fmaf(xv, wmw, a7.w); }

__global__ __launch_bounds__(128) void masked_embed_kernel(const float* __restrict__ xT,
                                                           const float* __restrict__ w,
                                                           const unsigned int* __restrict__ bm32,
                                                           float* __restrict__ part) {
    const int p4 = threadIdx.x;        // 0..127
    const int c  = blockIdx.x;         // 0..159  (interleaved g: rows c + 160*k)
    const int e  = blockIdx.y;

    const int WSTEP = NCHUNK * P4;     // floatx4 per g-step  (20480)
    const int BSTEP = NCHUNK * 16;     // bm dwords per step  (2560)
    const int XSTEP = NCHUNK * B_DIM;  // xT floats per step  (1280)

    const floatx4* __restrict__ wgp =
        reinterpret_cast<const floatx4*>(w) + (size_t)e * G_DIM * P4 + (size_t)c * P4 + p4;
    const unsigned int* __restrict__ bmp = bm32 + (size_t)c * 16 + (p4 >> 3);
    const float* __restrict__ xr = xT + (size_t)c * B_DIM;    // block-uniform
    const unsigned int sh = (p4 & 7) * 4;

    float4 a0 = make_float4(0.f, 0.f, 0.f, 0.f), a1 = a0, a2 = a0, a3 = a0,
           a4 = a0, a5 = a0, a6 = a0, a7 = a0;

#pragma unroll 1
    for (int k = 0; k < NITER / 5; ++k) {    // 25 iterations, 5 g-rows each
        unsigned int t0 = bmp[0 * BSTEP] >> sh;
        unsigned int t1 = bmp[1 * BSTEP] >> sh;
        unsigned int t2 = bmp[2 * BSTEP] >> sh;
        unsigned int t3 = bmp[3 * BSTEP] >> sh;
        unsigned int t4 = bmp[4 * BSTEP] >> sh;
        // DENSE nontemporal weight stream (A/B vs exec-masked skip): keeps the
        // HBM burst sequence unbroken; masking done purely in VALU via STEP.
        floatx4 w0 = __builtin_nontemporal_load(wgp + 0 * WSTEP);
        floatx4 w1 = __builtin_nontemporal_load(wgp + 1 * WSTEP);
        floatx4 w2 = __builtin_nontemporal_load(wgp + 2 * WSTEP);
        floatx4 w3 = __builtin_nontemporal_load(wgp + 3 * WSTEP);
        floatx4 w4 = __builtin_nontemporal_load(wgp + 4 * WSTEP);
        STEP(w0, t0, 0 * XSTEP)
        STEP(w1, t1, 1 * XSTEP)
        STEP(w2, t2, 2 * XSTEP)
        STEP(w3, t3, 3 * XSTEP)
        STEP(w4, t4, 4 * XSTEP)
        wgp += 5 * WSTEP; bmp += 5 * BSTEP; xr += 5 * XSTEP;
    }

    // contiguous partial store: part[(e*NCHUNK + c)][b][p]
    float* pb = part + (size_t)(e * NCHUNK + c) * B_DIM * P_DIM + p4 * 4;
#define PSTORE(acc, b) *reinterpret_cast<float4*>(pb + (size_t)(b) * P_DIM) = acc;
    PSTORE(a0, 0) PSTORE(a1, 1) PSTORE(a2, 2) PSTORE(a3, 3)
    PSTORE(a4, 4) PSTORE(a5, 5) PSTORE(a6, 6) PSTORE(a7, 7)
#undef PSTORE
}

// out[b][e][p] = bias[e][p] + sum_c part[(e*NCHUNK+c)][b][p]
__global__ __launch_bounds__(128) void reduce_kernel(const float* __restrict__ part,
                                                     const float* __restrict__ bias,
                                                     float* __restrict__ out) {
    const int p4 = threadIdx.x;   // 0..127
    const int e  = blockIdx.x;    // 0..15
    const int b  = blockIdx.y;    // 0..7

    const int CSTEP = B_DIM * P4; // float4 stride per c (1024)
    const float4* __restrict__ pp =
        reinterpret_cast<const float4*>(part) + ((size_t)(e * NCHUNK) * B_DIM + b) * P4 + p4;

    float4 s = make_float4(0.f, 0.f, 0.f, 0.f);
#pragma unroll 1
    for (int c = 0; c < NCHUNK; c += 8) {
        float4 q0 = pp[0 * CSTEP];
        float4 q1 = pp[1 * CSTEP];
        float4 q2 = pp[2 * CSTEP];
        float4 q3 = pp[3 * CSTEP];
        float4 q4 = pp[4 * CSTEP];
        float4 q5 = pp[5 * CSTEP];
        float4 q6 = pp[6 * CSTEP];
        float4 q7 = pp[7 * CSTEP];
        s.x += q0.x + q1.x + q2.x + q3.x + q4.x + q5.x + q6.x + q7.x;
        s.y += q0.y + q1.y + q2.y + q3.y + q4.y + q5.y + q6.y + q7.y;
        s.z += q0.z + q1.z + q2.z + q3.z + q4.z + q5.z + q6.z + q7.z;
        s.w += q0.w + q1.w + q2.w + q3.w + q4.w + q5.w + q6.w + q7.w;
        pp += 8 * CSTEP;
    }
    float4 bv = reinterpret_cast<const float4*>(bias)[e * P4 + p4];
    s.x += bv.x; s.y += bv.y; s.z += bv.z; s.w += bv.w;
    reinterpret_cast<float4*>(out)[((size_t)b * E_DIM + e) * P4 + p4] = s;
}

extern "C" void kernel_launch(void* const* d_in, const int* in_sizes, int n_in,
                              void* d_out, int out_size, void* d_ws, size_t ws_size,
                              hipStream_t stream) {
    const float* x    = (const float*)d_in[0];   // [B, G]
    const float* w    = (const float*)d_in[1];   // [E, G, P]
    const float* bias = (const float*)d_in[2];   // [E, P]
    const float* mask = (const float*)d_in[3];   // [G, P]
    float* out = (float*)d_out;                  // [B, E, P] fp32

    float* xT = (float*)((char*)d_ws + WS_XT_OFF);
    unsigned long long* bm = (unsigned long long*)((char*)d_ws + WS_BM_OFF);
    float* part = (float*)((char*)d_ws + WS_PART_OFF);

    prep_kernel<<<dim3((G_DIM * P_DIM) / 256), dim3(256), 0, stream>>>(x, mask, xT, bm);
    masked_embed_kernel<<<dim3(NCHUNK, E_DIM), dim3(128), 0, stream>>>(
        xT, w, (const unsigned int*)bm, part);
    reduce_kernel<<<dim3(E_DIM, B_DIM), dim3(128), 0, stream>>>(part, bias, out);
}

// Round 11
// 137.769 us; speedup vs baseline: 1.1815x; 1.0404x over previous
//
#include <hip/hip_runtime.h>

#define B_DIM 8
#define E_DIM 16
#define G_DIM 20000
#define P_DIM 512
#define P4    128             // float4 columns per P row
#define NCHUNK 160            // g-interleave stride; 20000 = 160*125 exactly
#define NITER  125            // rows per block (25 groups of 5)
// d_ws layout
#define WS_XT_OFF   0                 // 640 KB  xT  f32 [G][B]
#define WS_BM_OFF   (1u << 20)        // 1.28 MB packed mask bits
#define WS_PART_OFF (4u << 20)        // 40 MB   partials f32 [E*NCHUNK][B][P]

typedef float floatx4 __attribute__((ext_vector_type(4)));   // builtin-compatible

// Fused prepass: pack mask bits; threads with i<G also transpose x.
// bit j of bm[i>>6] <=> mask[(i&~63)+j] != 0   (grid = G*P/256 = 40000 exactly)
__global__ __launch_bounds__(256) void prep_kernel(const float* __restrict__ x,
                                                   const float* __restrict__ mask,
                                                   float* __restrict__ xT,
                                                   unsigned long long* __restrict__ bm) {
    int i = blockIdx.x * 256 + threadIdx.x;
    unsigned long long bal = __ballot(mask[i] != 0.0f);
    if ((threadIdx.x & 63) == 0) bm[i >> 6] = bal;
    if (i < G_DIM) {
#pragma unroll
        for (int b = 0; b < B_DIM; ++b)
            xT[i * B_DIM + b] = x[b * G_DIM + i];
    }
}

// one g-row: select 4 weight lanes by mask nibble, 8 batch FMAs
#define STEP(wv, t, xo) { \
    float wmx = ((t) & 1u) ? wv.x : 0.0f; \
    float wmy = ((t) & 2u) ? wv.y : 0.0f; \
    float wmz = ((t) & 4u) ? wv.z : 0.0f; \
    float wmw = ((t) & 8u) ? wv.w : 0.0f; \
    float xv; \
    xv = xr[(xo) + 0]; a0.x = fmaf(xv, wmx, a0.x); a0.y = fmaf(xv, wmy, a0.y); a0.z = fmaf(xv, wmz, a0.z); a0.w = fmaf(xv, wmw, a0.w); \
    xv = xr[(xo) + 1]; a1.x = fmaf(xv, wmx, a1.x); a1.y = fmaf(xv, wmy, a1.y); a1.z = fmaf(xv, wmz, a1.z); a1.w = fmaf(xv, wmw, a1.w); \
    xv = xr[(xo) + 2]; a2.x = fmaf(xv, wmx, a2.x); a2.y = fmaf(xv, wmy, a2.y); a2.z = fmaf(xv, wmz, a2.z); a2.w = fmaf(xv, wmw, a2.w); \
    xv = xr[(xo) + 3]; a3.x = fmaf(xv, wmx, a3.x); a3.y = fmaf(xv, wmy, a3.y); a3.z = fmaf(xv, wmz, a3.z); a3.w = fmaf(xv, wmw, a3.w); \
    xv = xr[(xo) + 4]; a4.x = fmaf(xv, wmx, a4.x); a4.y = fmaf(xv, wmy, a4.y); a4.z = fmaf(xv, wmz, a4.z); a4.w = fmaf(xv, wmw, a4.w); \
    xv = xr[(xo) + 5]; a5.x = fmaf(xv, wmx, a5.x); a5.y = fmaf(xv, wmy, a5.y); a5.z = fmaf(xv, wmz, a5.z); a5.w = fmaf(xv, wmw, a5.w); \
    xv = xr[(xo) + 6]; a6.x = fmaf(xv, wmx, a6.x); a6.y = fmaf(xv, wmy, a6.y); a6.z = fmaf(xv, wmz, a6.z); a6.w = fmaf(xv, wmw, a6.w); \
    xv = xr[(xo) + 7]; a7.x = fmaf(xv, wmx, a7.x); a7.y = fmaf(xv, wmy, a7.y); a7.z = fmaf(xv, wmz, a7.z); a7.w = fmaf(xv, wmw, a7.w); }

__global__ __launch_bounds__(128) void masked_embed_kernel(const float* __restrict__ xT,
                                                           const float* __restrict__ w,
                                                           const unsigned int* __restrict__ bm32,
                                                           float* __restrict__ part) {
    const int p4 = threadIdx.x;        // 0..127
    const int c  = blockIdx.x;         // 0..159  (interleaved g: rows c + 160*k)
    const int e  = blockIdx.y;

    const int WSTEP = NCHUNK * P4;     // floatx4 per g-step  (20480)
    const int BSTEP = NCHUNK * 16;     // bm dwords per step  (2560)
    const int XSTEP = NCHUNK * B_DIM;  // xT floats per step  (1280)

    const floatx4* __restrict__ wgp =
        reinterpret_cast<const floatx4*>(w) + (size_t)e * G_DIM * P4 + (size_t)c * P4 + p4;
    const unsigned int* __restrict__ bmp = bm32 + (size_t)c * 16 + (p4 >> 3);
    const float* __restrict__ xr = xT + (size_t)c * B_DIM;    // block-uniform
    const unsigned int sh = (p4 & 7) * 4;

    float4 a0 = make_float4(0.f, 0.f, 0.f, 0.f), a1 = a0, a2 = a0, a3 = a0,
           a4 = a0, a5 = a0, a6 = a0, a7 = a0;

#pragma unroll 1
    for (int k = 0; k < NITER / 5; ++k) {    // 25 iterations, 5 g-rows each
        unsigned int t0 = bmp[0 * BSTEP] >> sh;
        unsigned int t1 = bmp[1 * BSTEP] >> sh;
        unsigned int t2 = bmp[2 * BSTEP] >> sh;
        unsigned int t3 = bmp[3 * BSTEP] >> sh;
        unsigned int t4 = bmp[4 * BSTEP] >> sh;
        // exec-masked, nontemporal weight loads: lanes whose mask nibble is 0
        // issue no memory request; whole-sector skips cut HBM fetch.
        floatx4 w0 = (floatx4)0.0f, w1 = w0, w2 = w0, w3 = w0, w4 = w0;
        if (t0 & 15u) w0 = __builtin_nontemporal_load(wgp + 0 * WSTEP);
        if (t1 & 15u) w1 = __builtin_nontemporal_load(wgp + 1 * WSTEP);
        if (t2 & 15u) w2 = __builtin_nontemporal_load(wgp + 2 * WSTEP);
        if (t3 & 15u) w3 = __builtin_nontemporal_load(wgp + 3 * WSTEP);
        if (t4 & 15u) w4 = __builtin_nontemporal_load(wgp + 4 * WSTEP);
        STEP(w0, t0, 0 * XSTEP)
        STEP(w1, t1, 1 * XSTEP)
        STEP(w2, t2, 2 * XSTEP)
        STEP(w3, t3, 3 * XSTEP)
        STEP(w4, t4, 4 * XSTEP)
        wgp += 5 * WSTEP; bmp += 5 * BSTEP; xr += 5 * XSTEP;
    }

    // contiguous partial store: part[(e*NCHUNK + c)][b][p]
    float* pb = part + (size_t)(e * NCHUNK + c) * B_DIM * P_DIM + p4 * 4;
#define PSTORE(acc, b) *reinterpret_cast<float4*>(pb + (size_t)(b) * P_DIM) = acc;
    PSTORE(a0, 0) PSTORE(a1, 1) PSTORE(a2, 2) PSTORE(a3, 3)
    PSTORE(a4, 4) PSTORE(a5, 5) PSTORE(a6, 6) PSTORE(a7, 7)
#undef PSTORE
}

// out[b][e][p] = bias[e][p] + sum_c part[(e*NCHUNK+c)][b][p]
__global__ __launch_bounds__(128) void reduce_kernel(const float* __restrict__ part,
                                                     const float* __restrict__ bias,
                                                     float* __restrict__ out) {
    const int p4 = threadIdx.x;   // 0..127
    const int e  = blockIdx.x;    // 0..15
    const int b  = blockIdx.y;    // 0..7

    const int CSTEP = B_DIM * P4; // float4 stride per c (1024)
    const float4* __restrict__ pp =
        reinterpret_cast<const float4*>(part) + ((size_t)(e * NCHUNK) * B_DIM + b) * P4 + p4;

    float4 s = make_float4(0.f, 0.f, 0.f, 0.f);
#pragma unroll 1
    for (int c = 0; c < NCHUNK; c += 8) {
        float4 q0 = pp[0 * CSTEP];
        float4 q1 = pp[1 * CSTEP];
        float4 q2 = pp[2 * CSTEP];
        float4 q3 = pp[3 * CSTEP];
        float4 q4 = pp[4 * CSTEP];
        float4 q5 = pp[5 * CSTEP];
        float4 q6 = pp[6 * CSTEP];
        float4 q7 = pp[7 * CSTEP];
        s.x += q0.x + q1.x + q2.x + q3.x + q4.x + q5.x + q6.x + q7.x;
        s.y += q0.y + q1.y + q2.y + q3.y + q4.y + q5.y + q6.y + q7.y;
        s.z += q0.z + q1.z + q2.z + q3.z + q4.z + q5.z + q6.z + q7.z;
        s.w += q0.w + q1.w + q2.w + q3.w + q4.w + q5.w + q6.w + q7.w;
        pp += 8 * CSTEP;
    }
    float4 bv = reinterpret_cast<const float4*>(bias)[e * P4 + p4];
    s.x += bv.x; s.y += bv.y; s.z += bv.z; s.w += bv.w;
    reinterpret_cast<float4*>(out)[((size_t)b * E_DIM + e) * P4 + p4] = s;
}

extern "C" void kernel_launch(void* const* d_in, const int* in_sizes, int n_in,
                              void* d_out, int out_size, void* d_ws, size_t ws_size,
                              hipStream_t stream) {
    const float* x    = (const float*)d_in[0];   // [B, G]
    const float* w    = (const float*)d_in[1];   // [E, G, P]
    const float* bias = (const float*)d_in[2];   // [E, P]
    const float* mask = (const float*)d_in[3];   // [G, P]
    float* out = (float*)d_out;                  // [B, E, P] fp32

    float* xT = (float*)((char*)d_ws + WS_XT_OFF);
    unsigned long long* bm = (unsigned long long*)((char*)d_ws + WS_BM_OFF);
    float* part = (float*)((char*)d_ws + WS_PART_OFF);

    prep_kernel<<<dim3((G_DIM * P_DIM) / 256), dim3(256), 0, stream>>>(x, mask, xT, bm);
    masked_embed_kernel<<<dim3(NCHUNK, E_DIM), dim3(128), 0, stream>>>(
        xT, w, (const unsigned int*)bm, part);
    reduce_kernel<<<dim3(E_DIM, B_DIM), dim3(128), 0, stream>>>(part, bias, out);
}